// Round 11
// baseline (338.475 us; speedup 1.0000x reference)
//
#include <hip/hip_runtime.h>

// Fused chunked causal attention + RoPE for MI355X (gfx950).
// B=4, SLEN=4096, H=8, ZD=128, VD=256, CHUNK=1024 -> 16 chunks x 8 heads.
// Round 11: precompute K-RoPE->fp16 and V^T->fp16 into d_ws, then a main
// kernel whose staging is pure global_load_lds (async DMA, zero VALU) with
// counted-vmcnt 1-deep pipeline + raw s_barrier. Falls back to the r9 kernel
// if ws_size is too small. Compute core (swapped-QK 32x32 MFMA, in-register
// P, defer-max softmax) carried unchanged from r9.

#define NHEAD 8
#define ZDIM  128
#define VDIM  256
#define CHUNK 1024
#define QTILE 128
#define KT    32
#define NW    4

typedef _Float16 f16x8 __attribute__((ext_vector_type(8)));
typedef _Float16 f16x4 __attribute__((ext_vector_type(4)));
typedef __fp16   h16x2 __attribute__((ext_vector_type(2)));
typedef float    f32x4  __attribute__((ext_vector_type(4)));
typedef float    f32x16 __attribute__((ext_vector_type(16)));
typedef unsigned int u32;
typedef unsigned int u32x4 __attribute__((ext_vector_type(4)));

#define KSTRIDE 128
#define VSTRIDE 36
#define LOG2E   1.44269504088896f
#define RTHR    11.5415603f

#define KP_BYTES (128ULL * 1024 * 128 * 2)        /* 33.55 MB */
#define VT_BYTES (128ULL * 256 * 1024 * 2)        /* 67.11 MB */

// ------------------------- pre-kernel: K RoPE -> fp16 -------------------------
// Kp[ghead=cb*8+h][krow][128 halfs]
__global__ __launch_bounds__(256)
void prek(const float* __restrict__ xk, const float* __restrict__ cosT,
          const float* __restrict__ sinT, _Float16* __restrict__ Kp)
{
  const int gid = blockIdx.x * 256 + threadIdx.x;   // 2,097,152 total
  const int d0  = (gid & 15) * 8;
  const int hh  = (gid >> 4) & 7;
  const int row = gid >> 7;                         // 0..16383
  const int krow = row & 1023;
  const float* src = xk + (size_t)row * 1024 + hh * 128 + d0;
  f32x4 a  = *(const f32x4*)src;
  f32x4 b2 = *(const f32x4*)(src + 4);
  f32x4 cv = *(const f32x4*)(cosT + krow * 64 + (d0 >> 1));
  f32x4 sv = *(const f32x4*)(sinT + krow * 64 + (d0 >> 1));
  union { h16x2 h2[4]; u32x4 v; } o;
#pragma unroll
  for (int p = 0; p < 4; ++p) {
    const float xr = (p < 2 ? a[2 * p] : b2[2 * p - 4]);
    const float xi = (p < 2 ? a[2 * p + 1] : b2[2 * p - 3]);
    o.h2[p] = __builtin_amdgcn_cvt_pkrtz(xr * cv[p] - xi * sv[p],
                                         xr * sv[p] + xi * cv[p]);
  }
  const int ghead = (row >> 10) * 8 + hh;
  *(u32x4*)&Kp[((size_t)ghead * 1024 + krow) * 128 + d0] = o.v;
}

// ---------------------- pre-kernel: V transpose -> fp16 ----------------------
// Vt[ghead][vcol][1024 k halfs]; 64k x 64v tiles via LDS
__global__ __launch_bounds__(256)
void prev(const float* __restrict__ xv, _Float16* __restrict__ Vt)
{
  __shared__ float T[64][68];
  const int bid = blockIdx.x;                 // 8192
  const int vt  = bid & 3;
  const int ktile = (bid >> 2) & 15;
  const int hh  = (bid >> 6) & 7;
  const int cbb = bid >> 9;
  const int t = threadIdx.x;
  {
    const int kr2 = t >> 2, cg = (t & 3) * 16;
    const float* src = xv + ((size_t)(cbb * 1024 + ktile * 64 + kr2)) * 2048
                          + hh * 256 + vt * 64 + cg;
    f32x4 r0 = *(const f32x4*)(src);
    f32x4 r1 = *(const f32x4*)(src + 4);
    f32x4 r2 = *(const f32x4*)(src + 8);
    f32x4 r3 = *(const f32x4*)(src + 12);
    *(f32x4*)&T[kr2][cg]      = r0;
    *(f32x4*)&T[kr2][cg + 4]  = r1;
    *(f32x4*)&T[kr2][cg + 8]  = r2;
    *(f32x4*)&T[kr2][cg + 12] = r3;
  }
  __syncthreads();
  {
    const int vc2 = t >> 2, kg = (t & 3) * 16;
    union { h16x2 h2[8]; u32x4 v[2]; } o;
#pragma unroll
    for (int m = 0; m < 8; ++m)
      o.h2[m] = __builtin_amdgcn_cvt_pkrtz(T[kg + 2 * m][vc2], T[kg + 2 * m + 1][vc2]);
    _Float16* dst = Vt + ((size_t)((cbb * 8 + hh) * 256 + vt * 64 + vc2)) * 1024
                       + ktile * 64 + kg;
    *(u32x4*)(dst)     = o.v[0];
    *(u32x4*)(dst + 8) = o.v[1];
  }
}

// ------------------------------ async main kernel ----------------------------
__device__ __forceinline__ void gld16(const _Float16* g, _Float16* l) {
  __builtin_amdgcn_global_load_lds(
      (const __attribute__((address_space(1))) u32*)g,
      (__attribute__((address_space(3))) u32*)l, 16, 0, 0);
}

__global__ __launch_bounds__(256, 2)
void attn_pre(const float* __restrict__ xq, const _Float16* __restrict__ Kp,
              const _Float16* __restrict__ Vt, const float* __restrict__ cosT,
              const float* __restrict__ sinT, float* __restrict__ out)
{
  __shared__ _Float16 Klds[2][KT * 128];       // 16 KB
  __shared__ _Float16 Vlds[2][VDIM * 32];      // 32 KB

  const int b = (int)blockIdx.x;
  const int d = (b & 7) * 64 + (b >> 3);       // XCD grouping, bijective
  const int qpair = d & 3;
  const int ch = d >> 2;
  const int h  = ch & 7;
  const int cb = ch >> 3;
  const int ghead = cb * 8 + h;

  const int tid  = threadIdx.x;
  const int w    = tid >> 6;
  const int lane = tid & 63;
  const int l31  = lane & 31;
  const int hi   = lane >> 5;
  const int kswz = l31 & 7;

  const size_t row0 = (size_t)cb * CHUNK;
  const _Float16* Kph = Kp + (size_t)ghead * 1024 * 128;
  const _Float16* Vth = Vt + (size_t)ghead * 256 * 1024;

  // per-lane source offsets (halfs) for global_load_lds staging
  const int kr0  = w * 4 + (lane >> 4);            // rows 0..15 (inst0), +16 (inst1)
  const int slot = lane & 15;
  const int kchk = ((slot & 7) ^ (kr0 & 7)) | (slot & 8);
  const int koff = kr0 * 128 + kchk * 8;           // inst1 = +2048
  const int vcol0 = w * 16 + (lane >> 2);          // +64 per inst
  const int vs    = lane & 3;
  const int kbs   = vs ^ ((vcol0 >> 1) & 3);       // invariant across insts
  const int voff  = vcol0 * 1024 + kbs * 8;        // inst n = +n*65536

  int buf = 0;

#define STAGE(bufi, ktb_)                                            \
  do {                                                               \
    const _Float16* kb_ = Kph + (size_t)(ktb_) * 128 + koff;         \
    gld16(kb_,        &Klds[bufi][w * 512]);                         \
    gld16(kb_ + 2048, &Klds[bufi][2048 + w * 512]);                  \
    const _Float16* vb_ = Vth + (ktb_) + voff;                       \
    gld16(vb_,           &Vlds[bufi][w * 512]);                      \
    gld16(vb_ + 65536,   &Vlds[bufi][2048 + w * 512]);               \
    gld16(vb_ + 131072,  &Vlds[bufi][4096 + w * 512]);               \
    gld16(vb_ + 196608,  &Vlds[bufi][6144 + w * 512]);               \
  } while (0)

  for (int half = 0; half < 2; ++half) {
    const int qt = half ? qpair : (7 - qpair);
    const int wq0 = qt * QTILE + w * 32;
    const int qgr = wq0 + l31;

    buf = 0;
    STAGE(0, 0);   // prologue: tile 0 in flight

    // ---- Q -> registers as 32x32x16 B-frags (RoPE'd, pre-scaled by log2e) ----
    f16x8 qfrag[8];
    {
      const float* qp = xq + (row0 + qgr) * (size_t)(NHEAD * ZDIM) + h * ZDIM;
      const float* cq = cosT + qgr * (ZDIM / 2);
      const float* sq = sinT + qgr * (ZDIM / 2);
#pragma unroll
      for (int dblk = 0; dblk < 8; ++dblk) {
        const int d0 = dblk * 16 + hi * 8;
        f32x4 a  = *(const f32x4*)(qp + d0);
        f32x4 b2 = *(const f32x4*)(qp + d0 + 4);
        f32x4 cv = *(const f32x4*)(cq + (d0 >> 1));
        f32x4 sv = *(const f32x4*)(sq + (d0 >> 1));
        union { h16x2 h2[4]; f16x8 v; } fr;
#pragma unroll
        for (int p = 0; p < 4; ++p) {
          const float xr = (p < 2 ? a[2 * p] : b2[2 * p - 4]);
          const float xi = (p < 2 ? a[2 * p + 1] : b2[2 * p - 3]);
          fr.h2[p] = __builtin_amdgcn_cvt_pkrtz((xr * cv[p] - xi * sv[p]) * LOG2E,
                                                (xr * sv[p] + xi * cv[p]) * LOG2E);
        }
        qfrag[dblk] = fr.v;
      }
    }

    const f32x16 zf = {};
    f32x16 acc[8];
#pragma unroll
    for (int g = 0; g < 8; ++g) acc[g] = zf;
    float mrun = -1e30f;
    float lrun = 0.f;

    const int nkt = 4 * (qt + 1);

    for (int kt = 0; kt < nkt; ++kt) {
      const int ktb = kt * KT;
      // issue next tile's loads; wait only for current tile's 6 (counted vmcnt)
      if (kt + 1 < nkt) {
        STAGE(buf ^ 1, ktb + KT);
        asm volatile("s_waitcnt vmcnt(6)" ::: "memory");
      } else {
        asm volatile("s_waitcnt vmcnt(0)" ::: "memory");
      }
      __builtin_amdgcn_sched_barrier(0);
      __builtin_amdgcn_s_barrier();      // current tile visible to all waves

      if (ktb <= wq0 + 31) {
        // ---- S^T = K Q ----
        f32x16 s = {};
        __builtin_amdgcn_s_setprio(1);
#pragma unroll
        for (int dblk = 0; dblk < 8; ++dblk) {
          f16x8 kf = *(const f16x8*)&Klds[buf][l31 * 128 + (((dblk * 2 + hi) ^ kswz) * 8)];
          s = __builtin_amdgcn_mfma_f32_32x32x16_f16(kf, qfrag[dblk], s, 0, 0, 0);
        }
        __builtin_amdgcn_s_setprio(0);

        // ---- causal mask (partial tiles only) ----
        if (ktb + 31 > wq0) {
#pragma unroll
          for (int r = 0; r < 16; ++r) {
            const int kg = ktb + ((r & 3) + 8 * (r >> 2) + 4 * hi);
            if (kg > qgr) s[r] = -1.0e9f;
          }
        }

        // ---- softmax: lane-local max + one cross-half shuffle ----
        float m = s[0];
#pragma unroll
        for (int r = 1; r < 16; ++r) m = fmaxf(m, s[r]);
        m = fmaxf(m, __shfl_xor(m, 32));
        const bool need = (m > mrun + RTHR);
        if (__any(need)) {
          const float Mn = fmaxf(mrun, m);
          const float al = exp2f(mrun - Mn);
          mrun = Mn;
          lrun *= al;
#pragma unroll
          for (int r = 0; r < 16; ++r) {
            const float alr = __shfl(al, (r & 3) + 8 * (r >> 2) + 4 * hi);
#pragma unroll
            for (int g = 0; g < 8; ++g) acc[g][r] *= alr;
          }
        }
        float lsum = 0.f;
#pragma unroll
        for (int r = 0; r < 16; ++r) {
          s[r] = exp2f(s[r] - mrun);
          lsum += s[r];
        }
        lrun += lsum;

        // ---- P -> fp16 A-frags in registers, then PV ----
#pragma unroll
        for (int kb = 0; kb < 2; ++kb) {
          union { h16x2 h; u32 u; } A_, B_, C_, D_;
          A_.h = __builtin_amdgcn_cvt_pkrtz(s[8 * kb + 0], s[8 * kb + 1]);
          B_.h = __builtin_amdgcn_cvt_pkrtz(s[8 * kb + 2], s[8 * kb + 3]);
          C_.h = __builtin_amdgcn_cvt_pkrtz(s[8 * kb + 4], s[8 * kb + 5]);
          D_.h = __builtin_amdgcn_cvt_pkrtz(s[8 * kb + 6], s[8 * kb + 7]);
          const u32 G1 = hi ? A_.u : C_.u;
          const u32 G2 = hi ? B_.u : D_.u;
          const u32 G1s = (u32)__shfl_xor((int)G1, 32);
          const u32 G2s = (u32)__shfl_xor((int)G2, 32);
          union { u32 u[4]; f16x8 v; } af;
          af.u[0] = hi ? G1s : A_.u;
          af.u[1] = hi ? G2s : B_.u;
          af.u[2] = hi ? C_.u : G1s;
          af.u[3] = hi ? D_.u : G2s;
          __builtin_amdgcn_s_setprio(1);
#pragma unroll
          for (int g = 0; g < 8; ++g) {
            const int vcol = g * 32 + l31;
            const int srd = ((kb * 2 + hi) ^ ((vcol >> 1) & 3)) * 8;
            f16x8 bf = *(const f16x8*)&Vlds[buf][vcol * 32 + srd];
            acc[g] = __builtin_amdgcn_mfma_f32_32x32x16_f16(af.v, bf, acc[g], 0, 0, 0);
          }
          __builtin_amdgcn_s_setprio(0);
        }
      }
      __builtin_amdgcn_s_barrier();      // all reads of buf done before re-stage
      buf ^= 1;
    }

    // ---- epilogue ----
    const float ls = lrun + __shfl_xor(lrun, 32);
    const float linv = 1.0f / ls;
#pragma unroll
    for (int r = 0; r < 16; ++r) {
      const int qloc = (r & 3) + 8 * (r >> 2) + 4 * hi;
      const float lr = __shfl(linv, qloc);
      const size_t ob = (row0 + wq0 + qloc) * (size_t)(NHEAD * VDIM) + h * VDIM + l31;
#pragma unroll
      for (int g = 0; g < 8; ++g)
        out[ob + g * 32] = acc[g][r] * lr;
    }
    __builtin_amdgcn_s_barrier();        // half boundary
  }
#undef STAGE
}

// --------------------- fallback: r9 kernel (182 us, proven) -------------------
__global__ __launch_bounds__(256, 2)
void attn_fused(const float* __restrict__ xq, const float* __restrict__ xk,
                const float* __restrict__ xv, const float* __restrict__ cosT,
                const float* __restrict__ sinT, float* __restrict__ out)
{
  __shared__ _Float16 Klds[2][KT * KSTRIDE];
  __shared__ _Float16 Vlds[2][VDIM * VSTRIDE];

  const int b = (int)blockIdx.x;
  const int d = (b & 7) * 64 + (b >> 3);
  const int qpair = d & 3;
  const int ch = d >> 2;
  const int h  = ch & 7;
  const int cb = ch >> 3;

  const int tid  = threadIdx.x;
  const int w    = tid >> 6;
  const int lane = tid & 63;
  const int l31  = lane & 31;
  const int hi   = lane >> 5;
  const int vswz = (l31 >> 3) & 3;
  const int kswz = l31 & 7;

  const size_t row0 = (size_t)cb * CHUNK;

  const int kr    = tid >> 3;
  const int kt8   = tid & 7;
  const int vg    = tid >> 5;
  const int vc0   = (tid & 31) * 8;
  const int vsw   = tid & 3;
  const int vflip = ((tid >> 2) & 1) * 4;
  const int kblk  = vg >> 1;
  const int inb   = (vg & 1) * 4;

  int buf = 0;

  for (int half = 0; half < 2; ++half) {
    const int qt = half ? qpair : (7 - qpair);
    const int wq0 = qt * QTILE + w * 32;
    const int qgr = wq0 + l31;

    f16x8 qfrag[8];
    {
      const float* qp = xq + (row0 + qgr) * (size_t)(NHEAD * ZDIM) + h * ZDIM;
      const float* cq = cosT + qgr * (ZDIM / 2);
      const float* sq = sinT + qgr * (ZDIM / 2);
#pragma unroll
      for (int dblk = 0; dblk < 8; ++dblk) {
        const int d0 = dblk * 16 + hi * 8;
        f32x4 a  = *(const f32x4*)(qp + d0);
        f32x4 b2 = *(const f32x4*)(qp + d0 + 4);
        f32x4 cv = *(const f32x4*)(cq + (d0 >> 1));
        f32x4 sv = *(const f32x4*)(sq + (d0 >> 1));
        union { h16x2 h2[4]; f16x8 v; } fr;
#pragma unroll
        for (int p = 0; p < 4; ++p) {
          const float xr = (p < 2 ? a[2 * p] : b2[2 * p - 4]);
          const float xi = (p < 2 ? a[2 * p + 1] : b2[2 * p - 3]);
          fr.h2[p] = __builtin_amdgcn_cvt_pkrtz((xr * cv[p] - xi * sv[p]) * LOG2E,
                                                (xr * sv[p] + xi * cv[p]) * LOG2E);
        }
        qfrag[dblk] = fr.v;
      }
    }

    const f32x16 zf = {};
    f32x16 acc[8];
#pragma unroll
    for (int g = 0; g < 8; ++g) acc[g] = zf;
    float mrun = -1e30f;
    float lrun = 0.f;

    const int nkt = 4 * (qt + 1);

    for (int kt = 0; kt < nkt; ++kt) {
      const int ktb = kt * KT;
      {
        const int krow = ktb + kr;
        const float* kpb = xk + (row0 + krow) * (size_t)(NHEAD * ZDIM) + h * ZDIM;
        const float* ckb = cosT + krow * (ZDIM / 2);
        const float* skb = sinT + krow * (ZDIM / 2);
        f32x4 a0 = *(const f32x4*)(kpb + 8 * kt8);
        f32x4 a1 = *(const f32x4*)(kpb + 8 * kt8 + 4);
        f32x4 ca = *(const f32x4*)(ckb + 4 * kt8);
        f32x4 sa = *(const f32x4*)(skb + 4 * kt8);
        f32x4 b0 = *(const f32x4*)(kpb + 8 * kt8 + 64);
        f32x4 b1 = *(const f32x4*)(kpb + 8 * kt8 + 68);
        f32x4 cbv = *(const f32x4*)(ckb + 4 * kt8 + 32);
        f32x4 sbv = *(const f32x4*)(skb + 4 * kt8 + 32);
        union { h16x2 h2[4]; f16x8 v; } koA, koB;
#pragma unroll
        for (int p = 0; p < 4; ++p) {
          const float xrA = (p < 2 ? a0[2 * p] : a1[2 * p - 4]);
          const float xiA = (p < 2 ? a0[2 * p + 1] : a1[2 * p - 3]);
          koA.h2[p] = __builtin_amdgcn_cvt_pkrtz(xrA * ca[p] - xiA * sa[p],
                                                 xrA * sa[p] + xiA * ca[p]);
          const float xrB = (p < 2 ? b0[2 * p] : b1[2 * p - 4]);
          const float xiB = (p < 2 ? b0[2 * p + 1] : b1[2 * p - 3]);
          koB.h2[p] = __builtin_amdgcn_cvt_pkrtz(xrB * cbv[p] - xiB * sbv[p],
                                                 xrB * sbv[p] + xiB * cbv[p]);
        }
        const int sw = kr & 7;
        *(f16x8*)&Klds[buf][kr * KSTRIDE + ((kt8 ^ sw) * 8)]       = koA.v;
        *(f16x8*)&Klds[buf][kr * KSTRIDE + (((kt8 + 8) ^ sw) * 8)] = koB.v;
      }
      {
        const int vrow = ktb + vg * 4;
        const float* vp = xv + (row0 + vrow) * (size_t)(NHEAD * VDIM) + h * VDIM + vc0;
        f32x4 v0 = *(const f32x4*)(vp);         f32x4 v1 = *(const f32x4*)(vp + 4);
        f32x4 v2 = *(const f32x4*)(vp + 2048);  f32x4 v3 = *(const f32x4*)(vp + 2052);
        f32x4 v4 = *(const f32x4*)(vp + 4096);  f32x4 v5 = *(const f32x4*)(vp + 4100);
        f32x4 v6 = *(const f32x4*)(vp + 6144);  f32x4 v7 = *(const f32x4*)(vp + 6148);
#pragma unroll
        for (int ci = 0; ci < 8; ++ci) {
          const float e0 = (ci < 4 ? v0[ci] : v1[ci - 4]);
          const float e1 = (ci < 4 ? v2[ci] : v3[ci - 4]);
          const float e2 = (ci < 4 ? v4[ci] : v5[ci - 4]);
          const float e3 = (ci < 4 ? v6[ci] : v7[ci - 4]);
          union { h16x2 a2[2]; f16x4 v; } t;
          t.a2[0] = __builtin_amdgcn_cvt_pkrtz(e0, e1);
          t.a2[1] = __builtin_amdgcn_cvt_pkrtz(e2, e3);
          *(f16x4*)&Vlds[buf][(vc0 + ci) * VSTRIDE + ((kblk ^ vsw) * 8) + (inb ^ vflip)] = t.v;
        }
      }
      __syncthreads();

      if (ktb <= wq0 + 31) {
        f32x16 s = {};
        __builtin_amdgcn_s_setprio(1);
#pragma unroll
        for (int dblk = 0; dblk < 8; ++dblk) {
          f16x8 kf = *(const f16x8*)&Klds[buf][l31 * KSTRIDE + (((dblk * 2 + hi) ^ kswz) * 8)];
          s = __builtin_amdgcn_mfma_f32_32x32x16_f16(kf, qfrag[dblk], s, 0, 0, 0);
        }
        __builtin_amdgcn_s_setprio(0);

        if (ktb + 31 > wq0) {
#pragma unroll
          for (int r = 0; r < 16; ++r) {
            const int kg = ktb + ((r & 3) + 8 * (r >> 2) + 4 * hi);
            if (kg > qgr) s[r] = -1.0e9f;
          }
        }

        float m = s[0];
#pragma unroll
        for (int r = 1; r < 16; ++r) m = fmaxf(m, s[r]);
        m = fmaxf(m, __shfl_xor(m, 32));
        const bool need = (m > mrun + RTHR);
        if (__any(need)) {
          const float Mn = fmaxf(mrun, m);
          const float al = exp2f(mrun - Mn);
          mrun = Mn;
          lrun *= al;
#pragma unroll
          for (int r = 0; r < 16; ++r) {
            const float alr = __shfl(al, (r & 3) + 8 * (r >> 2) + 4 * hi);
#pragma unroll
            for (int g = 0; g < 8; ++g) acc[g][r] *= alr;
          }
        }
        float lsum = 0.f;
#pragma unroll
        for (int r = 0; r < 16; ++r) {
          s[r] = exp2f(s[r] - mrun);
          lsum += s[r];
        }
        lrun += lsum;

#pragma unroll
        for (int kb = 0; kb < 2; ++kb) {
          union { h16x2 h; u32 u; } A_, B_, C_, D_;
          A_.h = __builtin_amdgcn_cvt_pkrtz(s[8 * kb + 0], s[8 * kb + 1]);
          B_.h = __builtin_amdgcn_cvt_pkrtz(s[8 * kb + 2], s[8 * kb + 3]);
          C_.h = __builtin_amdgcn_cvt_pkrtz(s[8 * kb + 4], s[8 * kb + 5]);
          D_.h = __builtin_amdgcn_cvt_pkrtz(s[8 * kb + 6], s[8 * kb + 7]);
          const u32 G1 = hi ? A_.u : C_.u;
          const u32 G2 = hi ? B_.u : D_.u;
          const u32 G1s = (u32)__shfl_xor((int)G1, 32);
          const u32 G2s = (u32)__shfl_xor((int)G2, 32);
          union { u32 u[4]; f16x8 v; } af;
          af.u[0] = hi ? G1s : A_.u;
          af.u[1] = hi ? G2s : B_.u;
          af.u[2] = hi ? C_.u : G1s;
          af.u[3] = hi ? D_.u : G2s;
          __builtin_amdgcn_s_setprio(1);
#pragma unroll
          for (int g = 0; g < 8; ++g) {
            const int vcol = g * 32 + l31;
            const int ck = (((kb * 2 + hi) ^ vswz) * 8);
            const int fl = (g & 1) * 4;
            union { f16x4 h4[2]; f16x8 v; } bf;
            bf.h4[0] = *(const f16x4*)&Vlds[buf][vcol * VSTRIDE + ck + fl];
            bf.h4[1] = *(const f16x4*)&Vlds[buf][vcol * VSTRIDE + ck + (fl ^ 4)];
            acc[g] = __builtin_amdgcn_mfma_f32_32x32x16_f16(af.v, bf.v, acc[g], 0, 0, 0);
          }
          __builtin_amdgcn_s_setprio(0);
        }
      }
      buf ^= 1;
    }

    const float ls = lrun + __shfl_xor(lrun, 32);
    const float linv = 1.0f / ls;
#pragma unroll
    for (int r = 0; r < 16; ++r) {
      const int qloc = (r & 3) + 8 * (r >> 2) + 4 * hi;
      const float lr = __shfl(linv, qloc);
      const size_t ob = (row0 + wq0 + qloc) * (size_t)(NHEAD * VDIM) + h * VDIM + l31;
#pragma unroll
      for (int g = 0; g < 8; ++g)
        out[ob + g * 32] = acc[g][r] * lr;
    }
    __syncthreads();
  }
}

extern "C" void kernel_launch(void* const* d_in, const int* in_sizes, int n_in,
                              void* d_out, int out_size, void* d_ws, size_t ws_size,
                              hipStream_t stream) {
  const float* xq   = (const float*)d_in[0];
  const float* xk   = (const float*)d_in[1];
  const float* xv   = (const float*)d_in[2];
  const float* cosT = (const float*)d_in[4];
  const float* sinT = (const float*)d_in[5];
  float* out = (float*)d_out;

  if (ws_size >= (size_t)(KP_BYTES + VT_BYTES)) {
    _Float16* Kp = (_Float16*)d_ws;
    _Float16* Vt = (_Float16*)((char*)d_ws + KP_BYTES);
    prek<<<dim3(8192), dim3(256), 0, stream>>>(xk, cosT, sinT, Kp);
    prev<<<dim3(8192), dim3(256), 0, stream>>>(xv, Vt);
    attn_pre<<<dim3(512), dim3(256), 0, stream>>>(xq, Kp, Vt, cosT, sinT, out);
  } else {
    attn_fused<<<dim3(512), dim3(256), 0, stream>>>(xq, xk, xv, cosT, sinT, out);
  }
}

// Round 12
// 195.612 us; speedup vs baseline: 1.7303x; 1.7303x over previous
//
#include <hip/hip_runtime.h>

// Fused chunked causal attention + RoPE for MI355X (gfx950).
// B=4, SLEN=4096, H=8, ZD=128, VD=256, CHUNK=1024 -> 16 chunks x 8 heads.
// fp32 in/out; fp16 MFMA 32x32x16, fp32 accum.
// Round 12: r9 core (proven 182us) with KT=64 staged per barrier,
// single-buffered LDS: 32 independent loads/thread batched before the wait
// window (2x memory-level parallelism), two 32-k compute sub-tiles per stage.
// Barrier count per 64k unchanged. LDS 50KB -> 2 blocks/CU (reg-limited).

#define NHEAD 8
#define ZDIM  128
#define VDIM  256
#define CHUNK 1024
#define QTILE 128   // q rows per block (4 waves x 32)
#define KT64  64    // k rows staged per barrier
#define NW    4

typedef _Float16 f16x8 __attribute__((ext_vector_type(8)));
typedef _Float16 f16x4 __attribute__((ext_vector_type(4)));
typedef __fp16   h16x2 __attribute__((ext_vector_type(2)));   // cvt_pkrtz return type
typedef float    f32x4  __attribute__((ext_vector_type(4)));
typedef float    f32x16 __attribute__((ext_vector_type(16)));
typedef unsigned int u32;

#define KSTRIDE 128   // halfs per K-lds row (256B rows; chunk^(row&7) XOR swizzle)
#define VSTRIDE 68    // halfs per V^T-lds row (64 + 4 pad; 136B = 34dw, gcd(34,32)=2)
#define LOG2E   1.44269504088896f
#define RTHR    11.5415603f   /* 8 nats in log2 domain: defer-max threshold */

__global__ __launch_bounds__(256, 2)
void attn_fused(const float* __restrict__ xq, const float* __restrict__ xk,
                const float* __restrict__ xv, const float* __restrict__ cosT,
                const float* __restrict__ sinT, float* __restrict__ out)
{
  __shared__ _Float16 Klds[KT64 * KSTRIDE];    // 16.0 KB (single buffer)
  __shared__ _Float16 Vlds[VDIM * VSTRIDE];    // 34.0 KB (transposed, swizzled)
  // total 50.0 KB -> 2 blocks/CU (register-limited to 2 anyway)

  // XCD-grouping swizzle (bijective on [0,512))
  const int b = (int)blockIdx.x;
  const int d = (b & 7) * 64 + (b >> 3);
  const int qpair = d & 3;                       // 0..3 -> q-tiles {7-qpair, qpair}
  const int ch = d >> 2;                         // 0..127
  const int h  = ch & 7;
  const int cb = ch >> 3;

  const int tid  = threadIdx.x;
  const int w    = tid >> 6;                     // wave 0..3
  const int lane = tid & 63;
  const int l31  = lane & 31;
  const int hi   = lane >> 5;                    // 0/1
  const int vswz = (l31 >> 3) & 3;               // V read kblk XOR (2 bits)
  const int kswz = l31 & 7;                      // K read chunk XOR (row&7)

  const size_t row0 = (size_t)cb * CHUNK;

  // staging thread mapping (per 32-row pass)
  const int kr    = tid >> 3;             // K row 0..31 (within pass)
  const int kt8   = tid & 7;              // K chunk pair {kt8, kt8+8}
  const int vg    = tid >> 5;             // 0..7 -> V rows vg*4..+3 (within pass)
  const int vc0   = (tid & 31) * 8;       // V col group
  const int vsw   = tid & 3;              // V write kblk XOR (2 bits)
  const int vflip = ((tid >> 2) & 1) * 4; // V write sub-slot XOR ((vcol>>5)&1)*4
  const int kblk2 = vg >> 1;              // 0..3 within pass
  const int inb   = (vg & 1) * 4;

  for (int half = 0; half < 2; ++half) {
    const int qt = half ? qpair : (7 - qpair);   // heavy q-tile first
    const int wq0 = qt * QTILE + w * 32;         // wave's lowest q-row
    const int qgr = wq0 + l31;                   // this lane's q-row

    // ---- Q -> registers as 32x32x16 B-frags (RoPE'd, pre-scaled by log2e) ----
    f16x8 qfrag[8];
    {
      const float* qp = xq + (row0 + qgr) * (size_t)(NHEAD * ZDIM) + h * ZDIM;
      const float* cq = cosT + qgr * (ZDIM / 2);
      const float* sq = sinT + qgr * (ZDIM / 2);
#pragma unroll
      for (int dblk = 0; dblk < 8; ++dblk) {
        const int d0 = dblk * 16 + hi * 8;
        f32x4 a  = *(const f32x4*)(qp + d0);
        f32x4 b2 = *(const f32x4*)(qp + d0 + 4);
        f32x4 cv = *(const f32x4*)(cq + (d0 >> 1));
        f32x4 sv = *(const f32x4*)(sq + (d0 >> 1));
        union { h16x2 h2[4]; f16x8 v; } fr;
#pragma unroll
        for (int p = 0; p < 4; ++p) {
          const float xr = (p < 2 ? a[2 * p] : b2[2 * p - 4]);
          const float xi = (p < 2 ? a[2 * p + 1] : b2[2 * p - 3]);
          fr.h2[p] = __builtin_amdgcn_cvt_pkrtz((xr * cv[p] - xi * sv[p]) * LOG2E,
                                                (xr * sv[p] + xi * cv[p]) * LOG2E);
        }
        qfrag[dblk] = fr.v;
      }
    }

    const f32x16 zf = {};
    f32x16 acc[8];
#pragma unroll
    for (int g = 0; g < 8; ++g) acc[g] = zf;
    float mrun = -1e30f;
    float lrun = 0.f;

    const int n64 = 2 * (qt + 1);                // 64-row stage tiles

    for (int kt = 0; kt < n64; ++kt) {
      const int ktb64 = kt * KT64;
      __syncthreads();   // all reads of previous staged tile complete

      // ---- stage 64 K rows + 64 V rows in two 32-row passes ----
#pragma unroll
      for (int p2 = 0; p2 < 2; ++p2) {
        const int krow = ktb64 + p2 * 32 + kr;
        // K with RoPE; chunks {kt8, kt8+8}, slot = chunk ^ (row&7)
        {
          const float* kpb = xk + (row0 + krow) * (size_t)(NHEAD * ZDIM) + h * ZDIM;
          const float* ckb = cosT + krow * (ZDIM / 2);
          const float* skb = sinT + krow * (ZDIM / 2);
          f32x4 a0 = *(const f32x4*)(kpb + 8 * kt8);
          f32x4 a1 = *(const f32x4*)(kpb + 8 * kt8 + 4);
          f32x4 ca = *(const f32x4*)(ckb + 4 * kt8);
          f32x4 sa = *(const f32x4*)(skb + 4 * kt8);
          f32x4 b0 = *(const f32x4*)(kpb + 8 * kt8 + 64);
          f32x4 b1 = *(const f32x4*)(kpb + 8 * kt8 + 68);
          f32x4 cbv = *(const f32x4*)(ckb + 4 * kt8 + 32);
          f32x4 sbv = *(const f32x4*)(skb + 4 * kt8 + 32);
          union { h16x2 h2[4]; f16x8 v; } koA, koB;
#pragma unroll
          for (int p = 0; p < 4; ++p) {
            const float xrA = (p < 2 ? a0[2 * p] : a1[2 * p - 4]);
            const float xiA = (p < 2 ? a0[2 * p + 1] : a1[2 * p - 3]);
            koA.h2[p] = __builtin_amdgcn_cvt_pkrtz(xrA * ca[p] - xiA * sa[p],
                                                   xrA * sa[p] + xiA * ca[p]);
            const float xrB = (p < 2 ? b0[2 * p] : b1[2 * p - 4]);
            const float xiB = (p < 2 ? b0[2 * p + 1] : b1[2 * p - 3]);
            koB.h2[p] = __builtin_amdgcn_cvt_pkrtz(xrB * cbv[p] - xiB * sbv[p],
                                                   xrB * sbv[p] + xiB * cbv[p]);
          }
          const int lrow = p2 * 32 + kr;
          const int sw = lrow & 7;
          *(f16x8*)&Klds[lrow * KSTRIDE + ((kt8 ^ sw) * 8)]       = koA.v;
          *(f16x8*)&Klds[lrow * KSTRIDE + (((kt8 + 8) ^ sw) * 8)] = koB.v;
        }
        // V transposed; slot = ((kblk2 ^ vsw) & 3) + 4*p2, sub-slot inb^vflip
        {
          const int vrow = ktb64 + p2 * 32 + vg * 4;
          const float* vp = xv + (row0 + vrow) * (size_t)(NHEAD * VDIM) + h * VDIM + vc0;
          f32x4 v0 = *(const f32x4*)(vp);         f32x4 v1 = *(const f32x4*)(vp + 4);
          f32x4 v2 = *(const f32x4*)(vp + 2048);  f32x4 v3 = *(const f32x4*)(vp + 2052);
          f32x4 v4 = *(const f32x4*)(vp + 4096);  f32x4 v5 = *(const f32x4*)(vp + 4100);
          f32x4 v6 = *(const f32x4*)(vp + 6144);  f32x4 v7 = *(const f32x4*)(vp + 6148);
          const int slot = ((kblk2 ^ vsw) * 8) + p2 * 32;
#pragma unroll
          for (int ci = 0; ci < 8; ++ci) {
            const float e0 = (ci < 4 ? v0[ci] : v1[ci - 4]);
            const float e1 = (ci < 4 ? v2[ci] : v3[ci - 4]);
            const float e2 = (ci < 4 ? v4[ci] : v5[ci - 4]);
            const float e3 = (ci < 4 ? v6[ci] : v7[ci - 4]);
            union { h16x2 a2[2]; f16x4 v; } t;
            t.a2[0] = __builtin_amdgcn_cvt_pkrtz(e0, e1);
            t.a2[1] = __builtin_amdgcn_cvt_pkrtz(e2, e3);
            *(f16x4*)&Vlds[(vc0 + ci) * VSTRIDE + slot + (inb ^ vflip)] = t.v;
          }
        }
      }
      __syncthreads();   // staged tile visible

      // ---- two 32-k compute sub-tiles from the staged 64 rows ----
#pragma unroll
      for (int s2 = 0; s2 < 2; ++s2) {
        const int ktb = ktb64 + s2 * 32;
        if (ktb > wq0 + 31) continue;      // per-wave skip of fully-masked sub-tiles

        // ---- S^T = K Q : col=l31=q, row=k-local ----
        f32x16 s = {};
        __builtin_amdgcn_s_setprio(1);
#pragma unroll
        for (int dblk = 0; dblk < 8; ++dblk) {
          f16x8 kf = *(const f16x8*)&Klds[(s2 * 32 + l31) * KSTRIDE + (((dblk * 2 + hi) ^ kswz) * 8)];
          s = __builtin_amdgcn_mfma_f32_32x32x16_f16(kf, qfrag[dblk], s, 0, 0, 0);
        }
        __builtin_amdgcn_s_setprio(0);

        // ---- causal mask (partial sub-tiles only) ----
        if (ktb + 31 > wq0) {
#pragma unroll
          for (int r = 0; r < 16; ++r) {
            const int kg = ktb + ((r & 3) + 8 * (r >> 2) + 4 * hi);
            if (kg > qgr) s[r] = -1.0e9f;
          }
        }

        // ---- softmax: lane-local max + one cross-half shuffle ----
        float m = s[0];
#pragma unroll
        for (int r = 1; r < 16; ++r) m = fmaxf(m, s[r]);
        m = fmaxf(m, __shfl_xor(m, 32));
        const bool need = (m > mrun + RTHR);
        if (__any(need)) {
          const float Mn = fmaxf(mrun, m);
          const float al = exp2f(mrun - Mn);
          mrun = Mn;
          lrun *= al;
#pragma unroll
          for (int r = 0; r < 16; ++r) {
            const float alr = __shfl(al, (r & 3) + 8 * (r >> 2) + 4 * hi);
#pragma unroll
            for (int g = 0; g < 8; ++g) acc[g][r] *= alr;
          }
        }
        float lsum = 0.f;
#pragma unroll
        for (int r = 0; r < 16; ++r) {
          s[r] = exp2f(s[r] - mrun);
          lsum += s[r];
        }
        lrun += lsum;

        // ---- P -> fp16 A-frags in registers, then PV ----
#pragma unroll
        for (int kb = 0; kb < 2; ++kb) {
          union { h16x2 h; u32 u; } A_, B_, C_, D_;
          A_.h = __builtin_amdgcn_cvt_pkrtz(s[8 * kb + 0], s[8 * kb + 1]);
          B_.h = __builtin_amdgcn_cvt_pkrtz(s[8 * kb + 2], s[8 * kb + 3]);
          C_.h = __builtin_amdgcn_cvt_pkrtz(s[8 * kb + 4], s[8 * kb + 5]);
          D_.h = __builtin_amdgcn_cvt_pkrtz(s[8 * kb + 6], s[8 * kb + 7]);
          const u32 G1 = hi ? A_.u : C_.u;
          const u32 G2 = hi ? B_.u : D_.u;
          const u32 G1s = (u32)__shfl_xor((int)G1, 32);
          const u32 G2s = (u32)__shfl_xor((int)G2, 32);
          union { u32 u[4]; f16x8 v; } af;
          af.u[0] = hi ? G1s : A_.u;
          af.u[1] = hi ? G2s : B_.u;
          af.u[2] = hi ? C_.u : G1s;
          af.u[3] = hi ? D_.u : G2s;
          __builtin_amdgcn_s_setprio(1);
#pragma unroll
          for (int g = 0; g < 8; ++g) {
            const int vcol = g * 32 + l31;
            const int ck = (((kb * 2 + hi) ^ vswz) * 8) + s2 * 32;
            const int fl = (g & 1) * 4;   // matches write-side (vcol>>5)&1
            union { f16x4 h4[2]; f16x8 v; } bf;
            bf.h4[0] = *(const f16x4*)&Vlds[vcol * VSTRIDE + ck + fl];
            bf.h4[1] = *(const f16x4*)&Vlds[vcol * VSTRIDE + ck + (fl ^ 4)];
            acc[g] = __builtin_amdgcn_mfma_f32_32x32x16_f16(af.v, bf.v, acc[g], 0, 0, 0);
          }
          __builtin_amdgcn_s_setprio(0);
        }
      }
    }

    // ---- epilogue: denom reduce (1 shuffle), per-row linv broadcast, store ----
    const float ls = lrun + __shfl_xor(lrun, 32);
    const float linv = 1.0f / ls;
#pragma unroll
    for (int r = 0; r < 16; ++r) {
      const int qloc = (r & 3) + 8 * (r >> 2) + 4 * hi;
      const float lr = __shfl(linv, qloc);
      const size_t ob = (row0 + wq0 + qloc) * (size_t)(NHEAD * VDIM) + h * VDIM + l31;
#pragma unroll
      for (int g = 0; g < 8; ++g)
        out[ob + g * 32] = acc[g][r] * lr;
    }
    __syncthreads();   // half boundary: reads done before next half restages
  }
}

extern "C" void kernel_launch(void* const* d_in, const int* in_sizes, int n_in,
                              void* d_out, int out_size, void* d_ws, size_t ws_size,
                              hipStream_t stream) {
  const float* xq   = (const float*)d_in[0];
  const float* xk   = (const float*)d_in[1];
  const float* xv   = (const float*)d_in[2];
  // d_in[3] = mask (unused: causal mask computed analytically)
  const float* cosT = (const float*)d_in[4];
  const float* sinT = (const float*)d_in[5];
  float* out = (float*)d_out;

  dim3 grid(512);    // (4 qpairs) x (128 chunk*head), XCD-swizzled, 2 blocks/CU
  dim3 block(256);   // 4 waves
  attn_fused<<<grid, block, 0, stream>>>(xq, xk, xv, cosT, sinT, out);
}